// Round 9
// baseline (241.386 us; speedup 1.0000x reference)
//
#include <hip/hip_runtime.h>
#include <hip/hip_bf16.h>

// MHA layer. B=4, S=2048, HID=512, H=8, HD=64. fp32 in/out, bf16 MFMA inside.
// R9: attn identified as LDS-BANDWIDTH-bound (R6/R7/R8 ALU variants all ~82us;
// per-CU LDS traffic model matches dur). Fix: 32 queries/wave (2 Q-frag groups)
// -> K/V/bias LDS reads serve 2x work (traffic per query halved); V restaged
// fragment-major for K=16 PV frags (conflict-free, shared across q-groups).
// Grid (16,32)=512 blocks, 2/CU, LDS 24.5KB. GEMMs unchanged from R7.

typedef __bf16 v8bf __attribute__((ext_vector_type(8)));
typedef __bf16 v4bf __attribute__((ext_vector_type(4)));
typedef float  v4f  __attribute__((ext_vector_type(4)));
typedef short  v4s  __attribute__((ext_vector_type(4)));

#define MFMA16(a, b, c) __builtin_amdgcn_mfma_f32_16x16x32_bf16((a), (b), (c), 0, 0, 0)

// K=16 MFMA for PV: A,B = 4 bf16 (2 VGPRs), C/D = 4 f32.
__device__ inline v4f MFMA_PV(v4bf a, v4bf b, v4f c) {
    return __builtin_amdgcn_mfma_f32_16x16x16bf16_1k(
        __builtin_bit_cast(v4s, a), __builtin_bit_cast(v4s, b), c, 0, 0, 0);
}

// 0.125 * log2(e): folded into Wq/bq so softmax uses exp2 directly.
#define QSCALE 0.1803368801111f

__device__ inline v8bf cvt8(const float* __restrict__ p) {
    const v4f f0 = *(const v4f*)p;
    const v4f f1 = *(const v4f*)(p + 4);
    v8bf r;
    r[0] = (__bf16)f0[0]; r[1] = (__bf16)f0[1]; r[2] = (__bf16)f0[2]; r[3] = (__bf16)f0[3];
    r[4] = (__bf16)f1[0]; r[5] = (__bf16)f1[1]; r[6] = (__bf16)f1[2]; r[7] = (__bf16)f1[3];
    return r;
}

// ---------------------------------------------------------------------------
// K0: convert Wq,Wk,Wv,Wo (each 512x512 fp32) -> bf16, concatenated.
// Wq additionally scaled by QSCALE (softmax exp2 folding).
// ---------------------------------------------------------------------------
__global__ __launch_bounds__(256) void cvt_w(
    const float* __restrict__ Wq, const float* __restrict__ Wk,
    const float* __restrict__ Wv, const float* __restrict__ Wo,
    __bf16* __restrict__ out)
{
    const int idx = (blockIdx.x * 256 + threadIdx.x) * 4;
    const int w = idx >> 18, off = idx & 262143;
    const float* src = (w == 0) ? Wq : (w == 1) ? Wk : (w == 2) ? Wv : Wo;
    const float sc = (w == 0) ? QSCALE : 1.0f;
    const v4f x = *(const v4f*)(src + off);
    v4bf y;
    y[0] = (__bf16)(x[0] * sc); y[1] = (__bf16)(x[1] * sc);
    y[2] = (__bf16)(x[2] * sc); y[3] = (__bf16)(x[3] * sc);
    *(v4bf*)(out + idx) = y;
}

// ---------------------------------------------------------------------------
// K1: QKV projection (unchanged from R7). grid (64, 4, 3), block 256.
// ---------------------------------------------------------------------------
__global__ __launch_bounds__(256) void qkv_gemm(
    const float* __restrict__ xq, const float* __restrict__ xk, const float* __restrict__ xv,
    const __bf16* __restrict__ Wb,
    const float* __restrict__ bq, const float* __restrict__ bk, const float* __restrict__ bv,
    __bf16* __restrict__ Qo, __bf16* __restrict__ Ko, __bf16* __restrict__ VTo)
{
    const int z = blockIdx.z;
    const float*  x    = (z == 0) ? xq : (z == 1) ? xk : xv;
    const __bf16* W    = Wb + (size_t)z * 262144;
    const float*  bias = (z == 0) ? bq : (z == 1) ? bk : bv;
    const float   bsc  = (z == 0) ? QSCALE : 1.0f;

    const int tid = threadIdx.x, wave = tid >> 6, lane = tid & 63;
    const int quad = lane >> 4, r = lane & 15;
    const int wm = wave >> 1, wn = wave & 1;
    const int row0 = blockIdx.x * 128, col0 = blockIdx.y * 128;

    __shared__ __align__(16) __bf16 As[8192];
    __shared__ __align__(16) __bf16 Bs[8192];

    const float*  aptr[4];
    const __bf16* bptr[4];
    int adst[4], bdst[4];
    for (int j = 0; j < 4; j++) {
        const int e = tid + 256 * j;
        const int seg = e >> 6, ln = e & 63;
        aptr[j] = x + (size_t)(row0 + (seg >> 1) * 16 + (ln & 15)) * 512
                    + (seg & 1) * 32 + (ln >> 4) * 8;
        adst[j] = e * 8;
        const int segb = wave * 4 + j;
        bptr[j] = W + (size_t)(col0 + (segb >> 1) * 16 + r) * 512
                    + (segb & 1) * 32 + quad * 8;
        bdst[j] = (segb * 64 + lane) * 8;
    }

    v4f acc[4][4] = {};
    v8bf aReg[4], bReg[4];
    for (int j = 0; j < 4; j++) {
        aReg[j] = cvt8(aptr[j]);
        bReg[j] = *(const v8bf*)bptr[j];
    }

    for (int ki = 0; ki < 8; ki++) {
        __syncthreads();
        for (int j = 0; j < 4; j++) {
            *(v8bf*)&As[adst[j]] = aReg[j];
            *(v8bf*)&Bs[bdst[j]] = bReg[j];
        }
        __syncthreads();
        if (ki < 7) {
            const int kk = (ki + 1) * 64;
            for (int j = 0; j < 4; j++) {
                aReg[j] = cvt8(aptr[j] + kk);
                bReg[j] = *(const v8bf*)(bptr[j] + kk);
            }
        }
        for (int kc = 0; kc < 2; kc++) {
            v8bf a[4], b[4];
            for (int i = 0; i < 4; i++)
                a[i] = ((const v8bf*)As)[((wm * 4 + i) * 2 + kc) * 64 + lane];
            for (int i = 0; i < 4; i++)
                b[i] = ((const v8bf*)Bs)[((wn * 4 + i) * 2 + kc) * 64 + lane];
            for (int mi = 0; mi < 4; mi++)
                for (int ni = 0; ni < 4; ni++)
                    acc[mi][ni] = MFMA16(a[mi], b[ni], acc[mi][ni]);
        }
    }

    for (int ni = 0; ni < 4; ni++) {
        const int n = col0 + wn * 64 + ni * 16 + r;
        const float bv_ = bias[n] * bsc;
        const int hh = n >> 6, hd = n & 63;
        for (int mi = 0; mi < 4; mi++) {
            const int mbase = row0 + wm * 64 + mi * 16 + quad * 4;
            const int bb = mbase >> 11, s0 = mbase & 2047;
            if (z == 2) {
                v4bf pk;
                for (int i = 0; i < 4; i++)
                    pk[i] = (__bf16)(acc[mi][ni][i] + bv_);
                *(v4bf*)&VTo[((size_t)((bb * 8 + hh) * 64 + hd)) * 2048 + s0] = pk;
            } else {
                __bf16* dst = (z == 0) ? Qo : Ko;
                for (int i = 0; i < 4; i++)
                    dst[((size_t)((bb * 8 + hh) * 2048 + s0 + i)) * 64 + hd] =
                        (__bf16)(acc[mi][ni][i] + bv_);
            }
        }
    }
}

// ---------------------------------------------------------------------------
// K2: flash attention. 32 queries/wave (2 q-groups), 128 queries/block.
// grid (16, 32), block 256. K frag-major (K=32 S-frags), V frag-major
// (K=16 PV-frags). Streaming softmax (exp2, mask as C-init), transpose-free PV.
// ---------------------------------------------------------------------------
__global__ __launch_bounds__(256) void attn(
    const __bf16* __restrict__ Q, const __bf16* __restrict__ K,
    const __bf16* __restrict__ VT, const int* __restrict__ mask,
    __bf16* __restrict__ AO)
{
    const int bh = blockIdx.y, b = bh >> 3, h = bh & 7;
    const int tid = threadIdx.x, wave = tid >> 6, lane = tid & 63;
    const int quad = lane >> 4, r = lane & 15;
    const int q0 = blockIdx.x * 128 + wave * 32;

    const __bf16* Qb = Q  + (size_t)bh * 2048 * 64;
    const __bf16* Kb = K  + (size_t)bh * 2048 * 64;
    const __bf16* Vb = VT + (size_t)bh * 64 * 2048;
    const int*    mb = mask + (size_t)b * 2048;

    __shared__ __align__(16) __bf16 Kls[4096];   // 8 KB: K=32 frag-major
    __shared__ __align__(16) __bf16 Vls[4096];   // 8 KB: K=16 frag-major
    __shared__ float biasF[2048];                // 8 KB: 0 or -1e10 per key

    for (int i = tid; i < 2048; i += 256)
        biasF[i] = (mb[i] != 0) ? 0.f : -1e10f;

    // --- K staging: entry e (16B) = lane e&63 of segment e>>6 = (t_, hd-half)
    const int e1 = tid, e2 = tid + 256;
    int seg, l_, t_, h_;
    seg = e1 >> 6; l_ = e1 & 63; t_ = seg >> 1; h_ = seg & 1;
    const __bf16* kg1 = Kb + (size_t)(16 * t_ + (l_ & 15)) * 64 + h_ * 32 + (l_ >> 4) * 8;
    seg = e2 >> 6; l_ = e2 & 63; t_ = seg >> 1; h_ = seg & 1;
    const __bf16* kg2 = Kb + (size_t)(16 * t_ + (l_ & 15)) * 64 + h_ * 32 + (l_ >> 4) * 8;

    // --- V staging: entry e (8B) = lane e&63 of segment e>>6 = (t2, g):
    // VT[t2*16 + (l&15)][g*16 + (l>>4)*4 .. +3]
    const __bf16* vgp[4];
    int ve[4];
    for (int j = 0; j < 4; j++) {
        const int e = tid + 256 * j;
        const int s = e >> 6, l = e & 63;
        vgp[j] = Vb + (size_t)((s >> 2) * 16 + (l & 15)) * 2048 + (s & 3) * 16 + (l >> 4) * 4;
        ve[j] = e;
    }

    // Q fragments resident: 2 q-groups (q0+qg*16+r), pre-scaled via cvt_w/qkv
    v8bf qf[2][2];
    for (int qg = 0; qg < 2; qg++) {
        const __bf16* qp = Qb + (size_t)(q0 + qg * 16 + r) * 64;
        qf[qg][0] = *(const v8bf*)(qp +      quad * 8);
        qf[qg][1] = *(const v8bf*)(qp + 32 + quad * 8);
    }

    float ssum[2] = {0.f, 0.f};
    v4f o[2][4] = {};            // O^T per qg: lane holds hd=t2*16+quad*4+i, q=r

    // prologue: tile 0 -> regs
    v8bf ks1 = *(const v8bf*)kg1, ks2 = *(const v8bf*)kg2;
    v4bf vs[4];
    for (int j = 0; j < 4; j++) vs[j] = *(const v4bf*)vgp[j];

    for (int t = 0; t < 32; t++) {
        __syncthreads();                        // prev-tile readers done
        ((v8bf*)Kls)[e1] = ks1; ((v8bf*)Kls)[e2] = ks2;
        for (int j = 0; j < 4; j++) ((v4bf*)Vls)[ve[j]] = vs[j];
        __syncthreads();                        // tile t visible
        if (t < 31) {                           // prefetch t+1 -> regs
            const int k0n = (t + 1) * 64;
            ks1 = *(const v8bf*)(kg1 + (size_t)k0n * 64);
            ks2 = *(const v8bf*)(kg2 + (size_t)k0n * 64);
            for (int j = 0; j < 4; j++) vs[j] = *(const v4bf*)(vgp[j] + k0n);
        }
        const int k0 = t * 64;

        // ---- S^T + softmax: K-frags read ONCE, used by both q-groups
        v4bf pf[2][4];
        for (int tt = 0; tt < 4; tt++) {
            const v4f bias4 = *(const v4f*)&biasF[k0 + tt * 16 + quad * 4];
            v8bf kf0 = ((const v8bf*)Kls)[(tt * 2 + 0) * 64 + lane];
            v8bf kf1 = ((const v8bf*)Kls)[(tt * 2 + 1) * 64 + lane];
            for (int qg = 0; qg < 2; qg++) {
                v4f sa = MFMA16(kf0, qf[qg][0], bias4);
                sa = MFMA16(kf1, qf[qg][1], sa);
                for (int i = 0; i < 4; i++) {
                    const float p = exp2f(sa[i]);
                    ssum[qg] += p;
                    pf[qg][tt][i] = (__bf16)p;
                }
            }
        }

        // ---- O^T += VT x P^T : V-frags read ONCE, used by both q-groups
        for (int g = 0; g < 4; g++)
            for (int t2 = 0; t2 < 4; t2++) {
                const v4bf vf = ((const v4bf*)Vls)[(t2 * 4 + g) * 64 + lane];
                o[0][t2] = MFMA_PV(vf, pf[0][g], o[0][t2]);
                o[1][t2] = MFMA_PV(vf, pf[1][g], o[1][t2]);
            }
    }

    // ---- epilogue per q-group: reduce l over the 4 quads, packed v4bf stores
    for (int qg = 0; qg < 2; qg++) {
        float s = ssum[qg];
        s += __shfl_xor(s, 16);
        s += __shfl_xor(s, 32);
        const float inv = 1.0f / s;
        __bf16* dst = AO + ((size_t)b * 2048 + q0 + qg * 16 + r) * 512 + h * 64 + quad * 4;
        for (int t2 = 0; t2 < 4; t2++) {
            v4bf pk;
            for (int i = 0; i < 4; i++)
                pk[i] = (__bf16)(o[qg][t2][i] * inv);
            *(v4bf*)(dst + t2 * 16) = pk;
        }
    }
}

// ---------------------------------------------------------------------------
// K3: output projection (unchanged from R7). grid (64, 4), block 256.
// ---------------------------------------------------------------------------
__global__ __launch_bounds__(256) void out_gemm(
    const __bf16* __restrict__ Ai, const __bf16* __restrict__ W,
    const float* __restrict__ bias, float* __restrict__ y)
{
    const int tid = threadIdx.x, wave = tid >> 6, lane = tid & 63;
    const int quad = lane >> 4, r = lane & 15;
    const int wm = wave >> 1, wn = wave & 1;
    const int row0 = blockIdx.x * 128, col0 = blockIdx.y * 128;

    __shared__ __align__(16) __bf16 As[8192];
    __shared__ __align__(16) __bf16 Bs[8192];

    const __bf16* aptr[4];
    const __bf16* bptr[4];
    int dst_[4];
    for (int j = 0; j < 4; j++) {
        const int segb = wave * 4 + j;
        aptr[j] = Ai + (size_t)(row0 + (segb >> 1) * 16 + r) * 512 + (segb & 1) * 32 + quad * 8;
        bptr[j] = W  + (size_t)(col0 + (segb >> 1) * 16 + r) * 512 + (segb & 1) * 32 + quad * 8;
        dst_[j] = (segb * 64 + lane) * 8;
    }

    v4f acc[4][4] = {};
    v8bf aReg[4], bReg[4];
    for (int j = 0; j < 4; j++) {
        aReg[j] = *(const v8bf*)aptr[j];
        bReg[j] = *(const v8bf*)bptr[j];
    }

    for (int ki = 0; ki < 8; ki++) {
        __syncthreads();
        for (int j = 0; j < 4; j++) {
            *(v8bf*)&As[dst_[j]] = aReg[j];
            *(v8bf*)&Bs[dst_[j]] = bReg[j];
        }
        __syncthreads();
        if (ki < 7) {
            const int kk = (ki + 1) * 64;
            for (int j = 0; j < 4; j++) {
                aReg[j] = *(const v8bf*)(aptr[j] + kk);
                bReg[j] = *(const v8bf*)(bptr[j] + kk);
            }
        }
        for (int kc = 0; kc < 2; kc++) {
            v8bf a[4], b[4];
            for (int i = 0; i < 4; i++)
                a[i] = ((const v8bf*)As)[((wm * 4 + i) * 2 + kc) * 64 + lane];
            for (int i = 0; i < 4; i++)
                b[i] = ((const v8bf*)Bs)[((wn * 4 + i) * 2 + kc) * 64 + lane];
            for (int mi = 0; mi < 4; mi++)
                for (int ni = 0; ni < 4; ni++)
                    acc[mi][ni] = MFMA16(a[mi], b[ni], acc[mi][ni]);
        }
    }

    for (int ni = 0; ni < 4; ni++) {
        const int n = col0 + wn * 64 + ni * 16 + r;
        const float bv_ = bias[n];
        for (int mi = 0; mi < 4; mi++) {
            const int mbase = row0 + wm * 64 + mi * 16 + quad * 4;
            for (int i = 0; i < 4; i++)
                y[(size_t)(mbase + i) * 512 + n] = acc[mi][ni][i] + bv_;
        }
    }
}

// ---------------------------------------------------------------------------
extern "C" void kernel_launch(void* const* d_in, const int* in_sizes, int n_in,
                              void* d_out, int out_size, void* d_ws, size_t ws_size,
                              hipStream_t stream)
{
    const float* q    = (const float*)d_in[0];
    const float* k    = (const float*)d_in[1];
    const float* v    = (const float*)d_in[2];
    const int*   mask = (const int*)d_in[3];
    const float* Wq   = (const float*)d_in[4];
    const float* Wk   = (const float*)d_in[5];
    const float* Wv   = (const float*)d_in[6];
    const float* Wo   = (const float*)d_in[7];
    const float* bq   = (const float*)d_in[8];
    const float* bk   = (const float*)d_in[9];
    const float* bv   = (const float*)d_in[10];
    const float* bo   = (const float*)d_in[11];

    // ws (bf16 elems): Q[4M] K[4M] VT[4M] AO[4M] Wb[1M] -> 35.7 MB
    __bf16* ws  = (__bf16*)d_ws;
    __bf16* Qw  = ws;
    __bf16* Kw  = ws + 4194304;
    __bf16* VTw = ws + 8388608;
    __bf16* AOw = ws + 12582912;
    __bf16* Wb  = ws + 16777216;

    cvt_w<<<dim3(1024), 256, 0, stream>>>(Wq, Wk, Wv, Wo, Wb);
    qkv_gemm<<<dim3(64, 4, 3), 256, 0, stream>>>(q, k, v, Wb, bq, bk, bv, Qw, Kw, VTw);
    attn<<<dim3(16, 32), 256, 0, stream>>>(Qw, Kw, VTw, mask, AOw);
    out_gemm<<<dim3(64, 4), 256, 0, stream>>>(AOw, Wb + 786432, bo, (float*)d_out);
}